// Round 7
// baseline (18.051 us; speedup 1.0000x reference)
//
#include <hip/hip_runtime.h>
#include <hip/hip_bf16.h>

// velocity = MLP(concat[zone_embedding, person_attrs, time_vec])
// GCN layers in the reference are dead code (outputs unused) -> skipped.
//
// Round-7 = round-5 structure (2x16-zone tiles/wave, LB(256,3) for
// 3 blocks/CU residency -- round-6's LB(,2) cost a residency round) plus:
//  - wave-local preamble: time encoder + h1-base use per-wave LDS slices
//    with lgkmcnt/wave_barrier only; NO __syncthreads -> waves decouple.
//  - both tiles' X prefetched at kernel entry: t1's global latency hides
//    under preamble + tile-0 compute.
// Fragment math identical to verified round-5 (C/D map col=lane&15,
// row=(lane>>4)*4+reg; k=8g+j identically on A and B). N=16*6250 exactly
// -> no store guards; only the t1 prefetch address is clamped.

typedef __attribute__((ext_vector_type(8))) short bf16x8;
typedef __attribute__((ext_vector_type(4))) float f32x4;

#define BLK 256
#define WPB 4              // waves per block
#define H1S 72             // bf16 elems per H1 row: 64 + 8 pad
#define H2S 40             // 32 + 8 pad

__device__ __forceinline__ short f2bf(float x) {
    union { __hip_bfloat16 h; short s; } u;
    u.h = __float2bfloat16(x);
    return u.s;
}

#define WAVE_LDS_FENCE()                                   \
    __builtin_amdgcn_wave_barrier();                       \
    asm volatile("s_waitcnt lgkmcnt(0)" ::: "memory");     \
    __builtin_amdgcn_sched_barrier(0)

__global__ __launch_bounds__(BLK, 3) void zone_velocity_mfma(
    const float* __restrict__ tp,
    const float* __restrict__ emb,      // [N,32]
    const float* __restrict__ pa,       // [8]
    const float* __restrict__ Wt1, const float* __restrict__ bt1,
    const float* __restrict__ Wt2, const float* __restrict__ bt2,
    const float* __restrict__ Wd1, const float* __restrict__ bd1,  // [56,64],[64]
    const float* __restrict__ Wd2, const float* __restrict__ bd2,  // [64,32],[32]
    const float* __restrict__ Wd3, const float* __restrict__ bd3,  // [32,32],[32]
    float* __restrict__ out,            // [N,32]
    int N, int ntiles)
{
    __shared__ float s_u[WPB][16];
    __shared__ float s_tv[WPB][16];
    __shared__ float s_h1b[WPB][64];
    __shared__ __align__(16) short s_H1[WPB][16 * H1S];
    __shared__ __align__(16) short s_H2[WPB][16 * H2S];

    const int tidx = threadIdx.x;
    const int wave = tidx >> 6;
    const int lane = tidx & 63;
    const int c = lane & 15;   // A-row / B-col / D-col index
    const int g = lane >> 4;   // k-group (k = 8g + j)

    const int wid = blockIdx.x * WPB + wave;
    const int nw  = gridDim.x * WPB;          // 3128
    const int t0  = wid;                       // always < ntiles
    const int t1  = wid + nw;
    const bool has1 = (t1 < ntiles);

    // ---- prefetch X for BOTH tiles at entry ----
    float4 x0a, x0b, x1a, x1b;
    {
        const float* ep0 = emb + (size_t)(t0 * 16 + c) * 32 + 8 * g;
        x0a = *reinterpret_cast<const float4*>(ep0);
        x0b = *reinterpret_cast<const float4*>(ep0 + 4);
        int z1 = t1 * 16 + c; if (z1 >= N) z1 = N - 1;   // clamp inactive
        const float* ep1 = emb + (size_t)z1 * 32 + 8 * g;
        x1a = *reinterpret_cast<const float4*>(ep1);
        x1b = *reinterpret_cast<const float4*>(ep1 + 4);
    }

    // ---- weight fragments (loaded once; k = 8g+j on BOTH operands) ----
    bf16x8 w1f[4];        // Wd1[0:32] -> 4 n-tiles
    bf16x8 w2f[2][2];     // Wd2: 2 k-steps x 2 n-tiles
    bf16x8 w3f[2];        // Wd3: 2 n-tiles
    #pragma unroll
    for (int tt = 0; tt < 4; tt++)
        #pragma unroll
        for (int j = 0; j < 8; j++)
            w1f[tt][j] = f2bf(Wd1[(8 * g + j) * 64 + 16 * tt + c]);
    #pragma unroll
    for (int s = 0; s < 2; s++)
        #pragma unroll
        for (int tt = 0; tt < 2; tt++)
            #pragma unroll
            for (int j = 0; j < 8; j++)
                w2f[s][tt][j] = f2bf(Wd2[(32 * s + 8 * g + j) * 32 + 16 * tt + c]);
    #pragma unroll
    for (int tt = 0; tt < 2; tt++)
        #pragma unroll
        for (int j = 0; j < 8; j++)
            w3f[tt][j] = f2bf(Wd3[(8 * g + j) * 32 + 16 * tt + c]);

    // ---- wave-local preamble (no __syncthreads anywhere) ----
    const float tval = tp[0];
    if (lane < 16) s_u[wave][lane] = fmaxf(tval * Wt1[lane] + bt1[lane], 0.0f);
    WAVE_LDS_FENCE();
    if (lane < 16) {
        float a = bt2[lane];
        #pragma unroll
        for (int k = 0; k < 16; k++) a = fmaf(s_u[wave][k], Wt2[k * 16 + lane], a);
        s_tv[wave][lane] = a;   // no relu on second time layer
    }
    WAVE_LDS_FENCE();
    {   // h1 base: bd1 + person/time @ Wd1[32:56]; lane owns feature f=lane
        float a = bd1[lane];
        #pragma unroll
        for (int k = 0; k < 8; k++)
            a = fmaf(pa[k], Wd1[(32 + k) * 64 + lane], a);
        #pragma unroll
        for (int k = 0; k < 16; k++)
            a = fmaf(s_tv[wave][k], Wd1[(40 + k) * 64 + lane], a);
        s_h1b[wave][lane] = a;
    }
    WAVE_LDS_FENCE();

    float h1b[4];
    #pragma unroll
    for (int tt = 0; tt < 4; tt++) h1b[tt] = s_h1b[wave][16 * tt + c];
    float b2r[2] = { bd2[c], bd2[16 + c] };
    float b3r[2] = { bd3[c], bd3[16 + c] };

    short* H1 = s_H1[wave];
    short* H2 = s_H2[wave];

    auto run_tile = [&](int tile, const float4& xa, const float4& xb) {
        const int zb = tile * 16;

        bf16x8 af;
        af[0] = f2bf(xa.x); af[1] = f2bf(xa.y); af[2] = f2bf(xa.z); af[3] = f2bf(xa.w);
        af[4] = f2bf(xb.x); af[5] = f2bf(xb.y); af[6] = f2bf(xb.z); af[7] = f2bf(xb.w);

        // layer 1: H1[16,64] = relu(X @ Wd1[0:32] + h1b)
        f32x4 acc1[4];
        #pragma unroll
        for (int tt = 0; tt < 4; tt++) {
            f32x4 ci; ci[0] = ci[1] = ci[2] = ci[3] = h1b[tt];
            acc1[tt] = __builtin_amdgcn_mfma_f32_16x16x32_bf16(af, w1f[tt], ci, 0, 0, 0);
        }
        #pragma unroll
        for (int tt = 0; tt < 4; tt++)
            #pragma unroll
            for (int r = 0; r < 4; r++)
                H1[(4 * g + r) * H1S + 16 * tt + c] =
                    f2bf(fmaxf(acc1[tt][r], 0.0f));
        WAVE_LDS_FENCE();

        // layer 2: H2[16,32] = relu(H1 @ Wd2 + bd2), K=64 in 2 steps
        f32x4 acc2[2];
        #pragma unroll
        for (int tt = 0; tt < 2; tt++) {
            f32x4 ci; ci[0] = ci[1] = ci[2] = ci[3] = b2r[tt];
            acc2[tt] = ci;
        }
        #pragma unroll
        for (int s = 0; s < 2; s++) {
            bf16x8 a2 = *reinterpret_cast<const bf16x8*>(
                H1 + c * H1S + 32 * s + 8 * g);   // row=c, k=32s+8g+j
            #pragma unroll
            for (int tt = 0; tt < 2; tt++)
                acc2[tt] = __builtin_amdgcn_mfma_f32_16x16x32_bf16(
                    a2, w2f[s][tt], acc2[tt], 0, 0, 0);
        }
        #pragma unroll
        for (int tt = 0; tt < 2; tt++)
            #pragma unroll
            for (int r = 0; r < 4; r++)
                H2[(4 * g + r) * H2S + 16 * tt + c] =
                    f2bf(fmaxf(acc2[tt][r], 0.0f));
        WAVE_LDS_FENCE();

        // layer 3: O[16,32] = H2 @ Wd3 + bd3
        bf16x8 a3 = *reinterpret_cast<const bf16x8*>(H2 + c * H2S + 8 * g);
        f32x4 acc3[2];
        #pragma unroll
        for (int tt = 0; tt < 2; tt++) {
            f32x4 ci; ci[0] = ci[1] = ci[2] = ci[3] = b3r[tt];
            acc3[tt] = __builtin_amdgcn_mfma_f32_16x16x32_bf16(a3, w3f[tt], ci, 0, 0, 0);
        }

        // store: zone = zb + 4g + r (always < N: N = 16*ntiles exactly)
        #pragma unroll
        for (int r = 0; r < 4; r++) {
            float* op = out + (size_t)(zb + 4 * g + r) * 32;
            op[c]      = acc3[0][r];
            op[16 + c] = acc3[1][r];
        }
        WAVE_LDS_FENCE();   // H1/H2 reuse across tiles: order writes after reads
    };

    run_tile(t0, x0a, x0b);
    if (has1) run_tile(t1, x1a, x1b);
}

extern "C" void kernel_launch(void* const* d_in, const int* in_sizes, int n_in,
                              void* d_out, int out_size, void* d_ws, size_t ws_size,
                              hipStream_t stream) {
    // setup_inputs() order:
    //  0 t, 1 zone_embedding, 2 zone_features, 3 person_attrs, 4 edge_index,
    //  5 W1, 6 b1, 7 W2, 8 b2, 9 Wt1, 10 bt1, 11 Wt2, 12 bt2,
    // 13 Wd1, 14 bd1, 15 Wd2, 16 bd2, 17 Wd3, 18 bd3
    const float* t   = (const float*)d_in[0];
    const float* emb = (const float*)d_in[1];
    const float* pa  = (const float*)d_in[3];
    const float* Wt1 = (const float*)d_in[9];
    const float* bt1 = (const float*)d_in[10];
    const float* Wt2 = (const float*)d_in[11];
    const float* bt2 = (const float*)d_in[12];
    const float* Wd1 = (const float*)d_in[13];
    const float* bd1 = (const float*)d_in[14];
    const float* Wd2 = (const float*)d_in[15];
    const float* bd2 = (const float*)d_in[16];
    const float* Wd3 = (const float*)d_in[17];
    const float* bd3 = (const float*)d_in[18];

    const int N = in_sizes[1] / 32;          // 100000
    const int ntiles = (N + 15) / 16;        // 6250 (exact: 16*6250)
    float* out = (float*)d_out;

    // 782 blocks x 4 waves = 3128 waves, 2 tiles/wave, ~3 blocks/CU resident
    const int blocks = (ntiles + 2 * WPB - 1) / (2 * WPB);   // 782
    zone_velocity_mfma<<<blocks, BLK, 0, stream>>>(
        t, emb, pa, Wt1, bt1, Wt2, bt2,
        Wd1, bd1, Wd2, bd2, Wd3, bd3, out, N, ntiles);
}

// Round 8
// 16.986 us; speedup vs baseline: 1.0627x; 1.0627x over previous
//
#include <hip/hip_runtime.h>
#include <hip/hip_bf16.h>

// velocity = MLP(concat[zone_embedding, person_attrs, time_vec])
// GCN layers in the reference are dead code (outputs unused) -> skipped.
//
// Round-8 = EXACT round-5 structure (best measured: 15.56us) + two deltas:
//  1. weight-fragment loads + tile-0 X load hoisted to kernel ENTRY, so
//     their global latency overlaps the __syncthreads preamble chain
//     (round 5 issued them after sync #3 -> serial latency wall).
//  2. software-pipelined tile loop: next tile's X load issues at the top
//     of the current iteration, hiding under current-tile MFMA/LDS work.
// Everything else (block-wide preamble, LB(256,3) for 3 blocks/CU,
// 782-block grid, fence placement, fragment math) is round-5 verbatim.
// C/D map col=lane&15, row=(lane>>4)*4+reg; k=8g+j identical on A and B.

typedef __attribute__((ext_vector_type(8))) short bf16x8;
typedef __attribute__((ext_vector_type(4))) float f32x4;

#define BLK 256
#define WPB 4              // waves per block
#define H1S 72             // bf16 elems per H1 row: 64 + 8 pad
#define H2S 40             // 32 + 8 pad

__device__ __forceinline__ short f2bf(float x) {
    union { __hip_bfloat16 h; short s; } u;
    u.h = __float2bfloat16(x);
    return u.s;
}

#define WAVE_LDS_FENCE()                                   \
    __builtin_amdgcn_wave_barrier();                       \
    asm volatile("s_waitcnt lgkmcnt(0)" ::: "memory");     \
    __builtin_amdgcn_sched_barrier(0)

__global__ __launch_bounds__(BLK, 3) void zone_velocity_mfma(
    const float* __restrict__ tp,
    const float* __restrict__ emb,      // [N,32]
    const float* __restrict__ pa,       // [8]
    const float* __restrict__ Wt1, const float* __restrict__ bt1,
    const float* __restrict__ Wt2, const float* __restrict__ bt2,
    const float* __restrict__ Wd1, const float* __restrict__ bd1,  // [56,64],[64]
    const float* __restrict__ Wd2, const float* __restrict__ bd2,  // [64,32],[32]
    const float* __restrict__ Wd3, const float* __restrict__ bd3,  // [32,32],[32]
    float* __restrict__ out,            // [N,32]
    int N, int ntiles)
{
    __shared__ float s_u[16];
    __shared__ float s_tv[16];
    __shared__ float s_h1b[64];
    __shared__ __align__(16) short s_H1[WPB][16 * H1S];
    __shared__ __align__(16) short s_H2[WPB][16 * H2S];

    const int tidx = threadIdx.x;
    const int wave = tidx >> 6;
    const int lane = tidx & 63;
    const int c = lane & 15;   // A-row / B-col / D-col index
    const int g = lane >> 4;   // k-group (k = 8g + j)

    const int wid = blockIdx.x * WPB + wave;
    const int nw  = gridDim.x * WPB;          // 3128 waves

    // ---- DELTA 1a: tile-0 X load at entry (wid*16+c <= 3127*16+15 < N) ----
    float4 xa, xb;
    {
        const float* ep0 = emb + (size_t)(wid * 16 + c) * 32 + 8 * g;
        xa = *reinterpret_cast<const float4*>(ep0);
        xb = *reinterpret_cast<const float4*>(ep0 + 4);
    }

    // ---- DELTA 1b: weight fragments at entry (before the sync chain) ----
    bf16x8 w1f[4];        // Wd1[0:32] -> 4 n-tiles
    bf16x8 w2f[2][2];     // Wd2: 2 k-steps x 2 n-tiles
    bf16x8 w3f[2];        // Wd3: 2 n-tiles
    #pragma unroll
    for (int tt = 0; tt < 4; tt++)
        #pragma unroll
        for (int j = 0; j < 8; j++)
            w1f[tt][j] = f2bf(Wd1[(8 * g + j) * 64 + 16 * tt + c]);
    #pragma unroll
    for (int s = 0; s < 2; s++)
        #pragma unroll
        for (int tt = 0; tt < 2; tt++)
            #pragma unroll
            for (int j = 0; j < 8; j++)
                w2f[s][tt][j] = f2bf(Wd2[(32 * s + 8 * g + j) * 32 + 16 * tt + c]);
    #pragma unroll
    for (int tt = 0; tt < 2; tt++)
        #pragma unroll
        for (int j = 0; j < 8; j++)
            w3f[tt][j] = f2bf(Wd3[(8 * g + j) * 32 + 16 * tt + c]);

    // ---- time encoder (fp32 exact; block-wide, as round 5) ----
    const float tval = tp[0];
    if (tidx < 16) s_u[tidx] = fmaxf(tval * Wt1[tidx] + bt1[tidx], 0.0f);
    __syncthreads();
    if (tidx < 16) {
        float a = bt2[tidx];
        #pragma unroll
        for (int k = 0; k < 16; k++) a = fmaf(s_u[k], Wt2[k * 16 + tidx], a);
        s_tv[tidx] = a;  // no relu on second time layer
    }
    __syncthreads();

    // ---- h1 base: bd1 + person/time @ Wd1[32:56] (zone-uniform, fp32) ----
    if (tidx < 64) {
        float a = bd1[tidx];
        #pragma unroll
        for (int k = 0; k < 8; k++)
            a = fmaf(pa[k], Wd1[(32 + k) * 64 + tidx], a);
        #pragma unroll
        for (int k = 0; k < 16; k++)
            a = fmaf(s_tv[k], Wd1[(40 + k) * 64 + tidx], a);
        s_h1b[tidx] = a;
    }
    __syncthreads();

    // ---- per-lane biases ----
    float h1b[4];
    #pragma unroll
    for (int tt = 0; tt < 4; tt++) h1b[tt] = s_h1b[16 * tt + c];
    float b2r[2] = { bd2[c], bd2[16 + c] };
    float b3r[2] = { bd3[c], bd3[16 + c] };

    short* H1 = s_H1[wave];
    short* H2 = s_H2[wave];

    for (int tile = wid; tile < ntiles; tile += nw) {
        // ---- DELTA 2: prefetch next tile's X before computing this one ----
        const int tnext = tile + nw;
        float4 na, nb;
        {
            int zn = (tnext < ntiles) ? (tnext * 16 + c) : (tile * 16 + c);
            const float* ep = emb + (size_t)zn * 32 + 8 * g;
            na = *reinterpret_cast<const float4*>(ep);
            nb = *reinterpret_cast<const float4*>(ep + 4);
        }

        const int zb = tile * 16;

        bf16x8 af;
        af[0] = f2bf(xa.x); af[1] = f2bf(xa.y); af[2] = f2bf(xa.z); af[3] = f2bf(xa.w);
        af[4] = f2bf(xb.x); af[5] = f2bf(xb.y); af[6] = f2bf(xb.z); af[7] = f2bf(xb.w);

        // ---- layer 1: H1[16,64] = relu(X @ Wd1[0:32] + h1b) ----
        f32x4 acc1[4];
        #pragma unroll
        for (int tt = 0; tt < 4; tt++) {
            f32x4 ci; ci[0] = ci[1] = ci[2] = ci[3] = h1b[tt];
            acc1[tt] = __builtin_amdgcn_mfma_f32_16x16x32_bf16(af, w1f[tt], ci, 0, 0, 0);
        }
        #pragma unroll
        for (int tt = 0; tt < 4; tt++)
            #pragma unroll
            for (int r = 0; r < 4; r++)
                H1[(4 * g + r) * H1S + 16 * tt + c] =
                    f2bf(fmaxf(acc1[tt][r], 0.0f));
        WAVE_LDS_FENCE();

        // ---- layer 2: H2[16,32] = relu(H1 @ Wd2 + bd2), K=64 in 2 steps ----
        f32x4 acc2[2];
        #pragma unroll
        for (int tt = 0; tt < 2; tt++) {
            f32x4 ci; ci[0] = ci[1] = ci[2] = ci[3] = b2r[tt];
            acc2[tt] = ci;
        }
        #pragma unroll
        for (int s = 0; s < 2; s++) {
            bf16x8 a2 = *reinterpret_cast<const bf16x8*>(
                H1 + c * H1S + 32 * s + 8 * g);   // row=c, k=32s+8g+j
            #pragma unroll
            for (int tt = 0; tt < 2; tt++)
                acc2[tt] = __builtin_amdgcn_mfma_f32_16x16x32_bf16(
                    a2, w2f[s][tt], acc2[tt], 0, 0, 0);
        }
        #pragma unroll
        for (int tt = 0; tt < 2; tt++)
            #pragma unroll
            for (int r = 0; r < 4; r++)
                H2[(4 * g + r) * H2S + 16 * tt + c] =
                    f2bf(fmaxf(acc2[tt][r], 0.0f));
        WAVE_LDS_FENCE();

        // ---- layer 3: O[16,32] = H2 @ Wd3 + bd3 ----
        bf16x8 a3 = *reinterpret_cast<const bf16x8*>(H2 + c * H2S + 8 * g);
        f32x4 acc3[2];
        #pragma unroll
        for (int tt = 0; tt < 2; tt++) {
            f32x4 ci; ci[0] = ci[1] = ci[2] = ci[3] = b3r[tt];
            acc3[tt] = __builtin_amdgcn_mfma_f32_16x16x32_bf16(a3, w3f[tt], ci, 0, 0, 0);
        }

        // ---- store: zone = zb + 4g + r, channels c and 16+c ----
        #pragma unroll
        for (int r = 0; r < 4; r++) {
            const int zo = zb + 4 * g + r;
            if (zo < N) {
                float* op = out + (size_t)zo * 32;
                op[c]      = acc3[0][r];
                op[16 + c] = acc3[1][r];
            }
        }

        xa = na; xb = nb;   // rotate prefetched X into place
    }
}

extern "C" void kernel_launch(void* const* d_in, const int* in_sizes, int n_in,
                              void* d_out, int out_size, void* d_ws, size_t ws_size,
                              hipStream_t stream) {
    // setup_inputs() order:
    //  0 t, 1 zone_embedding, 2 zone_features, 3 person_attrs, 4 edge_index,
    //  5 W1, 6 b1, 7 W2, 8 b2, 9 Wt1, 10 bt1, 11 Wt2, 12 bt2,
    // 13 Wd1, 14 bd1, 15 Wd2, 16 bd2, 17 Wd3, 18 bd3
    const float* t   = (const float*)d_in[0];
    const float* emb = (const float*)d_in[1];
    const float* pa  = (const float*)d_in[3];
    const float* Wt1 = (const float*)d_in[9];
    const float* bt1 = (const float*)d_in[10];
    const float* Wt2 = (const float*)d_in[11];
    const float* bt2 = (const float*)d_in[12];
    const float* Wd1 = (const float*)d_in[13];
    const float* bd1 = (const float*)d_in[14];
    const float* Wd2 = (const float*)d_in[15];
    const float* bd2 = (const float*)d_in[16];
    const float* Wd3 = (const float*)d_in[17];
    const float* bd3 = (const float*)d_in[18];

    const int N = in_sizes[1] / 32;          // 100000
    const int ntiles = (N + 15) / 16;        // 6250
    float* out = (float*)d_out;

    // 782 blocks x 4 waves = 3128 waves, ~2 tiles/wave, ~3 blocks/CU resident
    const int blocks = 782;
    zone_velocity_mfma<<<blocks, BLK, 0, stream>>>(
        t, emb, pa, Wt1, bt1, Wt2, bt2,
        Wd1, bd1, Wd2, bd2, Wd3, bd3, out, N, ntiles);
}

// Round 9
// 13.902 us; speedup vs baseline: 1.2985x; 1.2219x over previous
//
#include <hip/hip_runtime.h>
#include <hip/hip_bf16.h>

// velocity = MLP(concat[zone_embedding, person_attrs, time_vec])
// GCN layers in the reference are dead code (outputs unused) -> skipped.
//
// Round-9: A/A reproducibility probe — byte-identical resubmission of the
// round-5 kernel (best measured: 15.56us). Rounds 6-8 tried three different
// restructures (macro-tile+ILP / wave-local preamble / hoisted+pipelined
// loads) and ALL measured worse (17.7/18.1/17.0us). This rerun separates
// H1 (round-5 schedule genuinely optimal; regressions real) from
// H2 (flat landscape; ~10us fixed launch overhead dominates and deltas are
// noise). Decision rule: <=15.9us -> H1, probe ws-precompute split next;
// >=16.5us -> H2, declare fixed-overhead floor with this kernel.
//
// Per wave: 16-zone tile, 10 x mfma_f32_16x16x32_bf16 (4 + 2x2 + 2).
// Inter-layer re-fragmentation via per-wave LDS tiles (bf16, padded strides
// 72/40 bf16 -> <=2-way bank aliasing = free). Only HW layout assumed is the
// verified C/D map: col=lane&15, row=(lane>>4)*4+reg. A/B k-indexing k=8g+j
// is applied identically to both operands -> correct under any internal
// slot->k routing (k-sum is reindex-invariant). Bias/person/time folded into
// fp32 C-init (exact).

typedef __attribute__((ext_vector_type(8))) short bf16x8;
typedef __attribute__((ext_vector_type(4))) float f32x4;

#define BLK 256
#define WPB 4              // waves per block
#define H1_STRIDE 72       // bf16 elems per row: 64 + 8 pad (bank spread)
#define H2_STRIDE 40       // 32 + 8 pad

__device__ __forceinline__ short f2bf(float x) {
    union { __hip_bfloat16 h; short s; } u;
    u.h = __float2bfloat16(x);
    return u.s;
}

__global__ __launch_bounds__(BLK, 3) void zone_velocity_mfma(
    const float* __restrict__ tp,
    const float* __restrict__ emb,      // [N,32]
    const float* __restrict__ pa,       // [8]
    const float* __restrict__ Wt1, const float* __restrict__ bt1,
    const float* __restrict__ Wt2, const float* __restrict__ bt2,
    const float* __restrict__ Wd1, const float* __restrict__ bd1,  // [56,64],[64]
    const float* __restrict__ Wd2, const float* __restrict__ bd2,  // [64,32],[32]
    const float* __restrict__ Wd3, const float* __restrict__ bd3,  // [32,32],[32]
    float* __restrict__ out,            // [N,32]
    int N, int ntiles)
{
    __shared__ float s_u[16];
    __shared__ float s_tv[16];
    __shared__ float s_h1b[64];
    __shared__ __align__(16) short s_H1[WPB][16 * H1_STRIDE];
    __shared__ __align__(16) short s_H2[WPB][16 * H2_STRIDE];

    const int tidx = threadIdx.x;
    const int wave = tidx >> 6;
    const int lane = tidx & 63;
    const int c = lane & 15;   // A-row / B-col / D-col index
    const int g = lane >> 4;   // k-group (k = 8g + j)

    // ---- time encoder (fp32 exact) ----
    const float tval = tp[0];
    if (tidx < 16) s_u[tidx] = fmaxf(tval * Wt1[tidx] + bt1[tidx], 0.0f);
    __syncthreads();
    if (tidx < 16) {
        float a = bt2[tidx];
        #pragma unroll
        for (int k = 0; k < 16; k++) a = fmaf(s_u[k], Wt2[k * 16 + tidx], a);
        s_tv[tidx] = a;  // no relu on second time layer
    }
    __syncthreads();

    // ---- h1 base: bd1 + person/time @ Wd1[32:56] (zone-uniform, fp32) ----
    if (tidx < 64) {
        float a = bd1[tidx];
        #pragma unroll
        for (int k = 0; k < 8; k++)
            a = fmaf(pa[k], Wd1[(32 + k) * 64 + tidx], a);
        #pragma unroll
        for (int k = 0; k < 16; k++)
            a = fmaf(s_tv[k], Wd1[(40 + k) * 64 + tidx], a);
        s_h1b[tidx] = a;
    }
    __syncthreads();

    // ---- per-lane biases ----
    float h1b[4];
    #pragma unroll
    for (int tt = 0; tt < 4; tt++) h1b[tt] = s_h1b[16 * tt + c];
    float b2r[2] = { bd2[c], bd2[16 + c] };
    float b3r[2] = { bd3[c], bd3[16 + c] };

    // ---- weight fragments (loaded once; k = 8g + j on BOTH operands) ----
    bf16x8 w1f[4];        // Wd1[0:32] -> 4 n-tiles
    bf16x8 w2f[2][2];     // Wd2: 2 k-steps x 2 n-tiles
    bf16x8 w3f[2];        // Wd3: 2 n-tiles
    #pragma unroll
    for (int tt = 0; tt < 4; tt++)
        #pragma unroll
        for (int j = 0; j < 8; j++)
            w1f[tt][j] = f2bf(Wd1[(8 * g + j) * 64 + 16 * tt + c]);
    #pragma unroll
    for (int s = 0; s < 2; s++)
        #pragma unroll
        for (int tt = 0; tt < 2; tt++)
            #pragma unroll
            for (int j = 0; j < 8; j++)
                w2f[s][tt][j] = f2bf(Wd2[(32 * s + 8 * g + j) * 32 + 16 * tt + c]);
    #pragma unroll
    for (int tt = 0; tt < 2; tt++)
        #pragma unroll
        for (int j = 0; j < 8; j++)
            w3f[tt][j] = f2bf(Wd3[(8 * g + j) * 32 + 16 * tt + c]);

    short* H1 = s_H1[wave];
    short* H2 = s_H2[wave];

    const int wid = blockIdx.x * WPB + wave;
    const int nw  = gridDim.x * WPB;

    for (int tile = wid; tile < ntiles; tile += nw) {
        const int zb = tile * 16;

        // ---- X fragment: row = c (zone), k = 8g+j (emb channel) ----
        const int zr  = zb + c;
        const int zrc = (zr < N) ? zr : (N - 1);
        const float* ep = emb + (size_t)zrc * 32 + 8 * g;
        float4 xa = *reinterpret_cast<const float4*>(ep);
        float4 xb = *reinterpret_cast<const float4*>(ep + 4);
        bf16x8 af;
        af[0] = f2bf(xa.x); af[1] = f2bf(xa.y); af[2] = f2bf(xa.z); af[3] = f2bf(xa.w);
        af[4] = f2bf(xb.x); af[5] = f2bf(xb.y); af[6] = f2bf(xb.z); af[7] = f2bf(xb.w);

        // ---- layer 1: H1[16,64] = relu(X @ Wd1[0:32] + h1b) ----
        f32x4 acc1[4];
        #pragma unroll
        for (int tt = 0; tt < 4; tt++) {
            f32x4 ci; ci[0] = ci[1] = ci[2] = ci[3] = h1b[tt];
            acc1[tt] = __builtin_amdgcn_mfma_f32_16x16x32_bf16(af, w1f[tt], ci, 0, 0, 0);
        }
        // relu -> LDS (D map: row m = 4g+r, col n = 16tt+c)
        #pragma unroll
        for (int tt = 0; tt < 4; tt++)
            #pragma unroll
            for (int r = 0; r < 4; r++)
                H1[(4 * g + r) * H1_STRIDE + 16 * tt + c] =
                    f2bf(fmaxf(acc1[tt][r], 0.0f));

        __builtin_amdgcn_wave_barrier();
        asm volatile("s_waitcnt lgkmcnt(0)" ::: "memory");
        __builtin_amdgcn_sched_barrier(0);

        // ---- layer 2: H2[16,32] = relu(H1 @ Wd2 + bd2), K=64 in 2 steps ----
        f32x4 acc2[2];
        #pragma unroll
        for (int tt = 0; tt < 2; tt++) {
            f32x4 ci; ci[0] = ci[1] = ci[2] = ci[3] = b2r[tt];
            acc2[tt] = ci;
        }
        #pragma unroll
        for (int s = 0; s < 2; s++) {
            bf16x8 a2 = *reinterpret_cast<const bf16x8*>(
                H1 + c * H1_STRIDE + 32 * s + 8 * g);   // row=c, k=32s+8g+j
            #pragma unroll
            for (int tt = 0; tt < 2; tt++)
                acc2[tt] = __builtin_amdgcn_mfma_f32_16x16x32_bf16(
                    a2, w2f[s][tt], acc2[tt], 0, 0, 0);
        }
        #pragma unroll
        for (int tt = 0; tt < 2; tt++)
            #pragma unroll
            for (int r = 0; r < 4; r++)
                H2[(4 * g + r) * H2_STRIDE + 16 * tt + c] =
                    f2bf(fmaxf(acc2[tt][r], 0.0f));

        __builtin_amdgcn_wave_barrier();
        asm volatile("s_waitcnt lgkmcnt(0)" ::: "memory");
        __builtin_amdgcn_sched_barrier(0);

        // ---- layer 3: O[16,32] = H2 @ Wd3 + bd3 ----
        bf16x8 a3 = *reinterpret_cast<const bf16x8*>(H2 + c * H2_STRIDE + 8 * g);
        f32x4 acc3[2];
        #pragma unroll
        for (int tt = 0; tt < 2; tt++) {
            f32x4 ci; ci[0] = ci[1] = ci[2] = ci[3] = b3r[tt];
            acc3[tt] = __builtin_amdgcn_mfma_f32_16x16x32_bf16(a3, w3f[tt], ci, 0, 0, 0);
        }

        // ---- store: zone = zb + 4g + r, channel = 16tt + c ----
        #pragma unroll
        for (int r = 0; r < 4; r++) {
            const int zo = zb + 4 * g + r;
            if (zo < N) {
                float* op = out + (size_t)zo * 32;
                op[c]      = acc3[0][r];
                op[16 + c] = acc3[1][r];
            }
        }
    }
}

extern "C" void kernel_launch(void* const* d_in, const int* in_sizes, int n_in,
                              void* d_out, int out_size, void* d_ws, size_t ws_size,
                              hipStream_t stream) {
    // setup_inputs() order:
    //  0 t, 1 zone_embedding, 2 zone_features, 3 person_attrs, 4 edge_index,
    //  5 W1, 6 b1, 7 W2, 8 b2, 9 Wt1, 10 bt1, 11 Wt2, 12 bt2,
    // 13 Wd1, 14 bd1, 15 Wd2, 16 bd2, 17 Wd3, 18 bd3
    const float* t   = (const float*)d_in[0];
    const float* emb = (const float*)d_in[1];
    const float* pa  = (const float*)d_in[3];
    const float* Wt1 = (const float*)d_in[9];
    const float* bt1 = (const float*)d_in[10];
    const float* Wt2 = (const float*)d_in[11];
    const float* bt2 = (const float*)d_in[12];
    const float* Wd1 = (const float*)d_in[13];
    const float* bd1 = (const float*)d_in[14];
    const float* Wd2 = (const float*)d_in[15];
    const float* bd2 = (const float*)d_in[16];
    const float* Wd3 = (const float*)d_in[17];
    const float* bd3 = (const float*)d_in[18];

    const int N = in_sizes[1] / 32;          // 100000
    const int ntiles = (N + 15) / 16;        // 6250
    float* out = (float*)d_out;

    // 782 blocks x 4 waves = 3128 waves, ~2 tiles/wave, ~3 blocks/CU
    const int blocks = 782;
    zone_velocity_mfma<<<blocks, BLK, 0, stream>>>(
        t, emb, pa, Wt1, bt1, Wt2, bt2,
        Wd1, bd1, Wd2, bd2, Wd3, bd3, out, N, ntiles);
}

// Round 10
// 12.981 us; speedup vs baseline: 1.3905x; 1.0709x over previous
//
#include <hip/hip_runtime.h>
#include <hip/hip_bf16.h>

// velocity = MLP(concat[zone_embedding, person_attrs, time_vec])
// GCN layers in the reference are dead code (outputs unused) -> skipped.
//
// Round-10: round-5/9 kernel (best: 13.9/15.6us A/A) with ONE delta:
// grid 782 -> 768. LB(256,3) => 3 blocks/CU residency => 768 concurrent
// blocks; a 782-block grid leaves a 14-block serial TAIL (~one block-time,
// ~7us) while 242 CUs idle -- matching measured 13.9us if block time ~7us.
// Grid=768 distributes the remainder as a 3rd tile on 106 waves (spread
// over distinct CUs, ~1-2us) instead. Decision rule: <=11.5us -> tail
// hypothesis confirmed; 13-16us -> latency floor, stop.
//
// Per wave: 16-zone tile, 10 x mfma_f32_16x16x32_bf16 (4 + 2x2 + 2).
// Inter-layer re-fragmentation via per-wave LDS tiles (bf16, padded strides
// 72/40 bf16 -> <=2-way bank aliasing = free). Only HW layout assumed is the
// verified C/D map: col=lane&15, row=(lane>>4)*4+reg. A/B k-indexing k=8g+j
// is applied identically to both operands -> correct under any internal
// slot->k routing (k-sum is reindex-invariant). Bias/person/time folded into
// fp32 C-init (exact).

typedef __attribute__((ext_vector_type(8))) short bf16x8;
typedef __attribute__((ext_vector_type(4))) float f32x4;

#define BLK 256
#define WPB 4              // waves per block
#define H1_STRIDE 72       // bf16 elems per row: 64 + 8 pad (bank spread)
#define H2_STRIDE 40       // 32 + 8 pad

__device__ __forceinline__ short f2bf(float x) {
    union { __hip_bfloat16 h; short s; } u;
    u.h = __float2bfloat16(x);
    return u.s;
}

__global__ __launch_bounds__(BLK, 3) void zone_velocity_mfma(
    const float* __restrict__ tp,
    const float* __restrict__ emb,      // [N,32]
    const float* __restrict__ pa,       // [8]
    const float* __restrict__ Wt1, const float* __restrict__ bt1,
    const float* __restrict__ Wt2, const float* __restrict__ bt2,
    const float* __restrict__ Wd1, const float* __restrict__ bd1,  // [56,64],[64]
    const float* __restrict__ Wd2, const float* __restrict__ bd2,  // [64,32],[32]
    const float* __restrict__ Wd3, const float* __restrict__ bd3,  // [32,32],[32]
    float* __restrict__ out,            // [N,32]
    int N, int ntiles)
{
    __shared__ float s_u[16];
    __shared__ float s_tv[16];
    __shared__ float s_h1b[64];
    __shared__ __align__(16) short s_H1[WPB][16 * H1_STRIDE];
    __shared__ __align__(16) short s_H2[WPB][16 * H2_STRIDE];

    const int tidx = threadIdx.x;
    const int wave = tidx >> 6;
    const int lane = tidx & 63;
    const int c = lane & 15;   // A-row / B-col / D-col index
    const int g = lane >> 4;   // k-group (k = 8g + j)

    // ---- time encoder (fp32 exact) ----
    const float tval = tp[0];
    if (tidx < 16) s_u[tidx] = fmaxf(tval * Wt1[tidx] + bt1[tidx], 0.0f);
    __syncthreads();
    if (tidx < 16) {
        float a = bt2[tidx];
        #pragma unroll
        for (int k = 0; k < 16; k++) a = fmaf(s_u[k], Wt2[k * 16 + tidx], a);
        s_tv[tidx] = a;  // no relu on second time layer
    }
    __syncthreads();

    // ---- h1 base: bd1 + person/time @ Wd1[32:56] (zone-uniform, fp32) ----
    if (tidx < 64) {
        float a = bd1[tidx];
        #pragma unroll
        for (int k = 0; k < 8; k++)
            a = fmaf(pa[k], Wd1[(32 + k) * 64 + tidx], a);
        #pragma unroll
        for (int k = 0; k < 16; k++)
            a = fmaf(s_tv[k], Wd1[(40 + k) * 64 + tidx], a);
        s_h1b[tidx] = a;
    }
    __syncthreads();

    // ---- per-lane biases ----
    float h1b[4];
    #pragma unroll
    for (int tt = 0; tt < 4; tt++) h1b[tt] = s_h1b[16 * tt + c];
    float b2r[2] = { bd2[c], bd2[16 + c] };
    float b3r[2] = { bd3[c], bd3[16 + c] };

    // ---- weight fragments (loaded once; k = 8g + j on BOTH operands) ----
    bf16x8 w1f[4];        // Wd1[0:32] -> 4 n-tiles
    bf16x8 w2f[2][2];     // Wd2: 2 k-steps x 2 n-tiles
    bf16x8 w3f[2];        // Wd3: 2 n-tiles
    #pragma unroll
    for (int tt = 0; tt < 4; tt++)
        #pragma unroll
        for (int j = 0; j < 8; j++)
            w1f[tt][j] = f2bf(Wd1[(8 * g + j) * 64 + 16 * tt + c]);
    #pragma unroll
    for (int s = 0; s < 2; s++)
        #pragma unroll
        for (int tt = 0; tt < 2; tt++)
            #pragma unroll
            for (int j = 0; j < 8; j++)
                w2f[s][tt][j] = f2bf(Wd2[(32 * s + 8 * g + j) * 32 + 16 * tt + c]);
    #pragma unroll
    for (int tt = 0; tt < 2; tt++)
        #pragma unroll
        for (int j = 0; j < 8; j++)
            w3f[tt][j] = f2bf(Wd3[(8 * g + j) * 32 + 16 * tt + c]);

    short* H1 = s_H1[wave];
    short* H2 = s_H2[wave];

    const int wid = blockIdx.x * WPB + wave;
    const int nw  = gridDim.x * WPB;

    for (int tile = wid; tile < ntiles; tile += nw) {
        const int zb = tile * 16;

        // ---- X fragment: row = c (zone), k = 8g+j (emb channel) ----
        const int zr  = zb + c;
        const int zrc = (zr < N) ? zr : (N - 1);
        const float* ep = emb + (size_t)zrc * 32 + 8 * g;
        float4 xa = *reinterpret_cast<const float4*>(ep);
        float4 xb = *reinterpret_cast<const float4*>(ep + 4);
        bf16x8 af;
        af[0] = f2bf(xa.x); af[1] = f2bf(xa.y); af[2] = f2bf(xa.z); af[3] = f2bf(xa.w);
        af[4] = f2bf(xb.x); af[5] = f2bf(xb.y); af[6] = f2bf(xb.z); af[7] = f2bf(xb.w);

        // ---- layer 1: H1[16,64] = relu(X @ Wd1[0:32] + h1b) ----
        f32x4 acc1[4];
        #pragma unroll
        for (int tt = 0; tt < 4; tt++) {
            f32x4 ci; ci[0] = ci[1] = ci[2] = ci[3] = h1b[tt];
            acc1[tt] = __builtin_amdgcn_mfma_f32_16x16x32_bf16(af, w1f[tt], ci, 0, 0, 0);
        }
        // relu -> LDS (D map: row m = 4g+r, col n = 16tt+c)
        #pragma unroll
        for (int tt = 0; tt < 4; tt++)
            #pragma unroll
            for (int r = 0; r < 4; r++)
                H1[(4 * g + r) * H1_STRIDE + 16 * tt + c] =
                    f2bf(fmaxf(acc1[tt][r], 0.0f));

        __builtin_amdgcn_wave_barrier();
        asm volatile("s_waitcnt lgkmcnt(0)" ::: "memory");
        __builtin_amdgcn_sched_barrier(0);

        // ---- layer 2: H2[16,32] = relu(H1 @ Wd2 + bd2), K=64 in 2 steps ----
        f32x4 acc2[2];
        #pragma unroll
        for (int tt = 0; tt < 2; tt++) {
            f32x4 ci; ci[0] = ci[1] = ci[2] = ci[3] = b2r[tt];
            acc2[tt] = ci;
        }
        #pragma unroll
        for (int s = 0; s < 2; s++) {
            bf16x8 a2 = *reinterpret_cast<const bf16x8*>(
                H1 + c * H1_STRIDE + 32 * s + 8 * g);   // row=c, k=32s+8g+j
            #pragma unroll
            for (int tt = 0; tt < 2; tt++)
                acc2[tt] = __builtin_amdgcn_mfma_f32_16x16x32_bf16(
                    a2, w2f[s][tt], acc2[tt], 0, 0, 0);
        }
        #pragma unroll
        for (int tt = 0; tt < 2; tt++)
            #pragma unroll
            for (int r = 0; r < 4; r++)
                H2[(4 * g + r) * H2_STRIDE + 16 * tt + c] =
                    f2bf(fmaxf(acc2[tt][r], 0.0f));

        __builtin_amdgcn_wave_barrier();
        asm volatile("s_waitcnt lgkmcnt(0)" ::: "memory");
        __builtin_amdgcn_sched_barrier(0);

        // ---- layer 3: O[16,32] = H2 @ Wd3 + bd3 ----
        bf16x8 a3 = *reinterpret_cast<const bf16x8*>(H2 + c * H2_STRIDE + 8 * g);
        f32x4 acc3[2];
        #pragma unroll
        for (int tt = 0; tt < 2; tt++) {
            f32x4 ci; ci[0] = ci[1] = ci[2] = ci[3] = b3r[tt];
            acc3[tt] = __builtin_amdgcn_mfma_f32_16x16x32_bf16(a3, w3f[tt], ci, 0, 0, 0);
        }

        // ---- store: zone = zb + 4g + r, channel = 16tt + c ----
        #pragma unroll
        for (int r = 0; r < 4; r++) {
            const int zo = zb + 4 * g + r;
            if (zo < N) {
                float* op = out + (size_t)zo * 32;
                op[c]      = acc3[0][r];
                op[16 + c] = acc3[1][r];
            }
        }
    }
}

extern "C" void kernel_launch(void* const* d_in, const int* in_sizes, int n_in,
                              void* d_out, int out_size, void* d_ws, size_t ws_size,
                              hipStream_t stream) {
    // setup_inputs() order:
    //  0 t, 1 zone_embedding, 2 zone_features, 3 person_attrs, 4 edge_index,
    //  5 W1, 6 b1, 7 W2, 8 b2, 9 Wt1, 10 bt1, 11 Wt2, 12 bt2,
    // 13 Wd1, 14 bd1, 15 Wd2, 16 bd2, 17 Wd3, 18 bd3
    const float* t   = (const float*)d_in[0];
    const float* emb = (const float*)d_in[1];
    const float* pa  = (const float*)d_in[3];
    const float* Wt1 = (const float*)d_in[9];
    const float* bt1 = (const float*)d_in[10];
    const float* Wt2 = (const float*)d_in[11];
    const float* bt2 = (const float*)d_in[12];
    const float* Wd1 = (const float*)d_in[13];
    const float* bd1 = (const float*)d_in[14];
    const float* Wd2 = (const float*)d_in[15];
    const float* bd2 = (const float*)d_in[16];
    const float* Wd3 = (const float*)d_in[17];
    const float* bd3 = (const float*)d_in[18];

    const int N = in_sizes[1] / 32;          // 100000
    const int ntiles = (N + 15) / 16;        // 6250
    float* out = (float*)d_out;

    // grid = 768 = 256 CUs x 3 blocks/CU (LB(256,3)): zero dispatch tail.
    // 3072 waves; all do 2 tiles, 106 waves take a 3rd (grid-stride loop).
    const int blocks = 768;
    zone_velocity_mfma<<<blocks, BLK, 0, stream>>>(
        t, emb, pa, Wt1, bt1, Wt2, bt2,
        Wd1, bd1, Wd2, bd2, Wd3, bd3, out, N, ntiles);
}